// Round 3
// baseline (133.696 us; speedup 1.0000x reference)
//
#include <hip/hip_runtime.h>

#define LSEQ 8194

typedef _Float16 f16x8 __attribute__((ext_vector_type(8)));
typedef _Float16 f16x2 __attribute__((ext_vector_type(2)));
typedef __attribute__((ext_vector_type(4))) float f32x4;

static __device__ __forceinline__ float tanh_fast(float x){
    float p = __expf(2.0f * x);
    float r = __builtin_amdgcn_rcpf(1.0f + p);
    return 1.0f - 2.0f * r;
}
// sum 3 packed-f16x2 taps + relu (v_pk_add_f16 + v_pk_max_f16)
static __device__ __forceinline__ unsigned h3relu(unsigned a, unsigned b, unsigned c){
    union { f16x2 h; unsigned u; } x, y, z, r;
    x.u = a; y.u = b; z.u = c;
    f16x2 s = x.h + y.h + z.h;
    f16x2 zero = { (_Float16)0.0f, (_Float16)0.0f };
    r.h = __builtin_elementwise_max(s, zero);
    return r.u;
}
static __device__ __forceinline__ unsigned hpack(float a, float b){
    union { f16x2 h; unsigned u; } pk;
    pk.h = (f16x2){ (_Float16)a, (_Float16)b };
    return pk.u;
}

// K_FUSED v4 — barrier-free waves + repaired schedule.
// Round-2 post-mortem: __launch_bounds__(512,6) capped VGPRs at ~85 (compiler
// hit 40) -> dt-outer/ki-inner MFMA loop serialized on per-MFMA LDS reads.
// v4: 256-thr blocks, bounds(256,3) (VGPR cap ~170, 3 blocks/CU by LDS),
// grid (16,128); wave w owns 32 positions as 2 tiles of 16. MFMA loop is
// ki-OUTER / dt-INNER: per ki, 8 independent ds_read_b128 A-frags then 8
// MFMAs into 8 distinct accumulators (dep distance 8 for LDS and acc chains).
// Accumulation order per acc[dt] remains ki-ascending -> bit-identical to the
// 97.4us kernel (same taps, same f16 packs, same ep/softmax/pool order;
// chunk c == position/32 mapping preserved so kb2 sums identically).
__global__ __launch_bounds__(256, 3) void k_fused(
        const int* __restrict__ seq, const float* __restrict__ emb,
        const float* __restrict__ cw, const float* __restrict__ cb,
        const float* __restrict__ Wa, const float* __restrict__ va,
        float* __restrict__ part, float* __restrict__ stats)
{
    __shared__ __align__(16) unsigned wahL[8192];      // 32 KB swizzled f16 Wa
    __shared__ __align__(16) unsigned tblH[1560];      // 6240 B perm tap table
    __shared__ unsigned short seqw16[4][132];          // pre-scaled offsets (x80)
    __shared__ __align__(16) float vaL[128];

    int tid = threadIdx.x;
    int b   = blockIdx.y;
    int x   = blockIdx.x;
    int n0  = x * 128;

    // ---- prologue (one barrier total) ----
    // Wa f32 -> f16 pairs (same pack order as before), row-XOR swizzle.
    for (int i = tid; i < 8192; i += 256){
        float2 t = ((const float2*)Wa)[i];
        unsigned byteoff = ((unsigned)i << 2) ^ ((((unsigned)i >> 6) & 7u) << 4);
        *(unsigned*)((char*)wahL + byteoff) = hpack(t.x, t.y);
    }
    if (tid < 128) vaL[tid] = va[tid];
    const int* sb = seq + (size_t)b * LSEQ;
    for (int i = tid; i < 4*132; i += 256){
        int s = i / 132, off = i - s*132;
        if (off < 130)
            seqw16[s][off] = (unsigned short)(sb[s*2048 + n0 + off] * 80);
    }
    // tap table straight from global (L2-hot), bit-identical FMA order
    for (int gid = tid; gid < 1248; gid += 256){
        int k = gid / 416;          // 416 = 26*16
        int rem = gid - k*416;
        int l = rem >> 4;
        int cp = rem & 15;
        int c0 = cp*2;
        float v0 = 0.f, v1 = 0.f;
        #pragma unroll
        for (int i = 0; i < 5; i++){
            float e = emb[l*5 + i];
            v0 += cw[(c0*5 + i)*3 + k] * e;
            v1 += cw[((c0+1)*5 + i)*3 + k] * e;
        }
        if (k == 2){ v0 += cb[c0]; v1 += cb[c0+1]; }
        tblH[k*520 + l*20 + (cp & 3)*4 + (cp >> 2)] = hpack(v0, v1);
    }
    __syncthreads();   // the ONLY barrier

    int w = tid >> 6, lane = tid & 63;
    int m = lane & 15, q = lane >> 4;
    const char* tb0 = (const char*)tblH + q*16;
    const char* tb1 = tb0 + 2080;
    const char* tb2 = tb1 + 2080;

    float accp[32];              // pooled partials, k = ki*32+q*8+t
    #pragma unroll
    for (int j = 0; j < 32; j++) accp[j] = 0.f;
    float Mw = -3e38f, Sw = 0.f;

    #pragma unroll
    for (int it = 0; it < 2; it++){
        int base = w*32 + it*16 + m;
        uint4 vfr[4];            // B-frags: lane's own position, 4 K-tiles
        {
            unsigned V[4][4];    // V[s][ki] = f16x2(chA,chB); cp=ki*4+q
            #pragma unroll
            for (int s = 0; s < 4; s++){
                unsigned oa = seqw16[s][base];
                unsigned ob = seqw16[s][base+1];
                unsigned oc = seqw16[s][base+2];
                uint4 t0 = *(const uint4*)(tb0 + oa);
                uint4 t1 = *(const uint4*)(tb1 + ob);
                uint4 t2 = *(const uint4*)(tb2 + oc);
                V[s][0] = h3relu(t0.x, t1.x, t2.x);
                V[s][1] = h3relu(t0.y, t1.y, t2.y);
                V[s][2] = h3relu(t0.z, t1.z, t2.z);
                V[s][3] = h3relu(t0.w, t1.w, t2.w);
            }
            #pragma unroll
            for (int ki = 0; ki < 4; ki++){
                uint4 o;
                o.x = __builtin_amdgcn_perm(V[1][ki], V[0][ki], 0x05040100u);  // A_s0,A_s1
                o.y = __builtin_amdgcn_perm(V[3][ki], V[2][ki], 0x05040100u);  // A_s2,A_s3
                o.z = __builtin_amdgcn_perm(V[1][ki], V[0][ki], 0x07060302u);  // B_s0,B_s1
                o.w = __builtin_amdgcn_perm(V[3][ki], V[2][ki], 0x07060302u);  // B_s2,B_s3
                vfr[ki] = o;
            }
        }

        // full d_out in-wave: ki-outer / dt-inner, 8 indep acc chains
        f32x4 acc[8];
        #pragma unroll
        for (int dt = 0; dt < 8; dt++) acc[dt] = (f32x4){0.f, 0.f, 0.f, 0.f};
        #pragma unroll
        for (int ki = 0; ki < 4; ki++){
            uint4 af[8];
            #pragma unroll
            for (int dt = 0; dt < 8; dt++){
                unsigned abyte = (unsigned)((dt*16 + m)*256 + ki*64 + q*16)
                               ^ (((unsigned)(m & 7)) << 4);
                af[dt] = *(const uint4*)((const char*)wahL + abyte);
            }
            union { uint4 u; f16x8 f; } bf; bf.u = vfr[ki];
            #pragma unroll
            for (int dt = 0; dt < 8; dt++){
                union { uint4 u; f16x8 f; } a; a.u = af[dt];
                acc[dt] = __builtin_amdgcn_mfma_f32_16x16x32_f16(a.f, bf.f, acc[dt], 0, 0, 0);
            }
        }

        // e-partial: same summation order as before (dt asc, elem asc)
        float ep = 0.f;
        #pragma unroll
        for (int dt = 0; dt < 8; dt++){
            const f32x4 vg = *(const f32x4*)&vaL[dt*16 + q*4];
            ep += vg[0] * tanh_fast(acc[dt][0]);
            ep += vg[1] * tanh_fast(acc[dt][1]);
            ep += vg[2] * tanh_fast(acc[dt][2]);
            ep += vg[3] * tanh_fast(acc[dt][3]);
        }
        ep += __shfl_xor(ep, 16);
        ep += __shfl_xor(ep, 32);        // e[col m], replicated across q

        // online softmax over this 16-position tile (16-lane butterfly)
        float msub = ep;
        #pragma unroll
        for (int off = 8; off >= 1; off >>= 1)
            msub = fmaxf(msub, __shfl_xor(msub, off));
        float Mnew = fmaxf(Mw, msub);
        float alpha = __expf(Mw - Mnew);
        float wrl = __expf(ep - Mnew);   // weight of THIS lane's own position
        float ssub = wrl;
        #pragma unroll
        for (int off = 8; off >= 1; off >>= 1) ssub += __shfl_xor(ssub, off);
        Sw = alpha * Sw + ssub;
        Mw = Mnew;

        // pool from the lane's OWN V registers (no LDS, no shfl)
        #pragma unroll
        for (int ki = 0; ki < 4; ki++){
            union { uint4 u; f16x2 h[4]; } vv; vv.u = vfr[ki];
            accp[ki*8 + 0] = alpha * accp[ki*8 + 0] + wrl * (float)vv.h[0][0];
            accp[ki*8 + 1] = alpha * accp[ki*8 + 1] + wrl * (float)vv.h[0][1];
            accp[ki*8 + 2] = alpha * accp[ki*8 + 2] + wrl * (float)vv.h[1][0];
            accp[ki*8 + 3] = alpha * accp[ki*8 + 3] + wrl * (float)vv.h[1][1];
            accp[ki*8 + 4] = alpha * accp[ki*8 + 4] + wrl * (float)vv.h[2][0];
            accp[ki*8 + 5] = alpha * accp[ki*8 + 5] + wrl * (float)vv.h[2][1];
            accp[ki*8 + 6] = alpha * accp[ki*8 + 6] + wrl * (float)vv.h[3][0];
            accp[ki*8 + 7] = alpha * accp[ki*8 + 7] + wrl * (float)vv.h[3][1];
        }
    }

    // reduce accp over the 16 position-lanes (m); k-slice differs only by q
    #pragma unroll
    for (int j = 0; j < 32; j++){
        accp[j] += __shfl_xor(accp[j], 1);
        accp[j] += __shfl_xor(accp[j], 2);
        accp[j] += __shfl_xor(accp[j], 4);
        accp[j] += __shfl_xor(accp[j], 8);
    }
    size_t chunk = ((size_t)b*16 + x)*4 + w;      // 64 chunks per b, c = pos/32
    if (m == 0){
        float* pd = part + chunk*128;
        #pragma unroll
        for (int ki = 0; ki < 4; ki++){
            float4 lo = { accp[ki*8+0], accp[ki*8+1], accp[ki*8+2], accp[ki*8+3] };
            float4 hi = { accp[ki*8+4], accp[ki*8+5], accp[ki*8+6], accp[ki*8+7] };
            *(float4*)(pd + ki*32 + q*8)     = lo;   // 16B-aligned (elem%4==0)
            *(float4*)(pd + ki*32 + q*8 + 4) = hi;
        }
    }
    if (lane == 0){
        stats[chunk*2    ] = Mw;
        stats[chunk*2 + 1] = Sw;
    }
}

// KB2: combine 64 chunk partials per b with softmax rescale.
// out[b][d] = sum_c part[b][c][d]*exp(m_c-M) / sum_c s_c*exp(m_c-M)
__global__ __launch_bounds__(128) void kb2_finish(const float* __restrict__ part,
        const float* __restrict__ stats, float* __restrict__ out)
{
    int b = blockIdx.x, d = threadIdx.x;
    const float* st = stats + (size_t)b*128;
    float M = -3e38f;
    #pragma unroll 8
    for (int c = 0; c < 64; c++) M = fmaxf(M, st[c*2]);
    const float* p = part + (size_t)b*64*128 + d;
    float S = 0.f, s = 0.f;
    #pragma unroll 4
    for (int c = 0; c < 64; c++){
        float f = __expf(st[c*2] - M);
        S += st[c*2+1] * f;
        s += p[c*128] * f;
    }
    float inv = 1.0f / S;
    out[b*128 + d] = s * inv;
}

extern "C" void kernel_launch(void* const* d_in, const int* in_sizes, int n_in,
                              void* d_out, int out_size, void* d_ws, size_t ws_size,
                              hipStream_t stream)
{
    const int*   seq = (const int*)d_in[0];
    const float* emb = (const float*)d_in[1];
    const float* cw  = (const float*)d_in[2];
    const float* cb  = (const float*)d_in[3];
    const float* Wa  = (const float*)d_in[4];
    const float* va  = (const float*)d_in[5];
    float* out = (float*)d_out;

    char* wsb = (char*)d_ws;
    float* part  = (float*)wsb;                  // 4 MiB (128*64*128 f32)
    float* stats = (float*)(wsb + (8<<20));      // 64 KiB (128*64*2 f32)

    k_fused   <<<dim3(16,128), 256, 0, stream>>>(seq, emb, cw, cb, Wa, va, part, stats);
    kb2_finish<<<128,          128, 0, stream>>>(part, stats, out);
}

// Round 4
// 107.330 us; speedup vs baseline: 1.2457x; 1.2457x over previous
//
#include <hip/hip_runtime.h>

#define LSEQ 8194

typedef _Float16 f16x8 __attribute__((ext_vector_type(8)));
typedef _Float16 f16x2 __attribute__((ext_vector_type(2)));
typedef __attribute__((ext_vector_type(4))) float f32x4;

static __device__ __forceinline__ float tanh_fast(float x){
    float p = __expf(2.0f * x);
    float r = __builtin_amdgcn_rcpf(1.0f + p);
    return 1.0f - 2.0f * r;
}
// sum 3 packed-f16x2 taps + relu (v_pk_add_f16 + v_pk_max_f16)
static __device__ __forceinline__ unsigned h3relu(unsigned a, unsigned b, unsigned c){
    union { f16x2 h; unsigned u; } x, y, z, r;
    x.u = a; y.u = b; z.u = c;
    f16x2 s = x.h + y.h + z.h;
    f16x2 zero = { (_Float16)0.0f, (_Float16)0.0f };
    r.h = __builtin_elementwise_max(s, zero);
    return r.u;
}
static __device__ __forceinline__ unsigned hpack(float a, float b){
    union { f16x2 h; unsigned u; } pk;
    pk.h = (f16x2){ (_Float16)a, (_Float16)b };
    return pk.u;
}

// K_SETUP: precompute (once) the LDS images k_fused will linearly copy:
//  tblG: perm-layout tap table, 1560 u32 (word index k*520+l*20+(cp&3)*4+(cp>>2))
//  wahG: f16 Wa pairs at XOR-swizzled byte offsets (the exact LDS image)
__global__ __launch_bounds__(256) void k_setup(
        const float* __restrict__ emb, const float* __restrict__ cw,
        const float* __restrict__ cb, const float* __restrict__ Wa,
        unsigned* __restrict__ tblG, unsigned* __restrict__ wahG)
{
    int gid = blockIdx.x*256 + threadIdx.x;
    if (gid < 1248){
        int k = gid / 416;          // 416 = 26*16
        int rem = gid - k*416;
        int l = rem >> 4;
        int cp = rem & 15;
        int c0 = cp*2;
        float v0 = 0.f, v1 = 0.f;
        #pragma unroll
        for (int i = 0; i < 5; i++){
            float e = emb[l*5 + i];
            v0 += cw[(c0*5 + i)*3 + k] * e;
            v1 += cw[((c0+1)*5 + i)*3 + k] * e;
        }
        if (k == 2){ v0 += cb[c0]; v1 += cb[c0+1]; }
        tblG[k*520 + l*20 + (cp & 3)*4 + (cp >> 2)] = hpack(v0, v1);
    }
    for (int i = gid; i < 8192; i += 1280){
        float2 t = ((const float2*)Wa)[i];
        unsigned byteoff = ((unsigned)i << 2) ^ ((((unsigned)i >> 6) & 7u) << 4);
        *(unsigned*)((char*)wahG + byteoff) = hpack(t.x, t.y);
    }
}

// K_FUSED v5 — barrier-free waves, spill-free register plan.
// Rounds 2/3 post-mortem: __launch_bounds__ arg2 caps VGPR at 512/(2*arg2)
// (observed: (256,4)->64, (512,6)->40, (256,3)->84). v4's live set ~120 at
// cap 84 -> 9 dwords/thread scratch spill (WRITE_SIZE 19MB) -> 67us.
// v5: bounds(256,2) (cap 128); dt tiles split in two halves of 4 so peak
// live = accp(32)+vfr(16)+acc(16)+af(16)+misc ~ 95; LDS 40576B -> exactly
// 4 blocks/CU (16 waves). Prologue is a pure linear uint4 copy of the
// precomputed LDS images (zero convert VALU). Math order identical to the
// 97.4us kernel (same taps, same f16 packs, ki-ascending accumulation,
// same ep/softmax/pool order) -> bit-identical output expected.
__global__ __launch_bounds__(256, 2) void k_fused(
        const int* __restrict__ seq, const unsigned* __restrict__ tblG,
        const unsigned* __restrict__ wahG, const float* __restrict__ va,
        float* __restrict__ part, float* __restrict__ stats)
{
    __shared__ __align__(16) unsigned wahL[8192];      // 32 KB swizzled f16 Wa
    __shared__ __align__(16) unsigned tblH[1560];      // 6240 B perm tap table
    __shared__ unsigned short seqw16[4][132];          // pre-scaled offsets (x80)
    __shared__ __align__(16) float vaL[128];

    int tid = threadIdx.x;
    int b   = blockIdx.y;
    int x   = blockIdx.x;
    int n0  = x * 128;

    // ---- prologue: pure copies (one barrier total) ----
    #pragma unroll
    for (int j = 0; j < 8; j++)
        ((uint4*)wahL)[tid + j*256] = ((const uint4*)wahG)[tid + j*256];
    for (int i = tid; i < 390; i += 256)
        ((uint4*)tblH)[i] = ((const uint4*)tblG)[i];
    if (tid < 128) vaL[tid] = va[tid];
    const int* sb = seq + (size_t)b * LSEQ;
    for (int i = tid; i < 4*132; i += 256){
        int s = i / 132, off = i - s*132;
        if (off < 130)
            seqw16[s][off] = (unsigned short)(sb[s*2048 + n0 + off] * 80);
    }
    __syncthreads();   // the ONLY barrier

    int w = tid >> 6, lane = tid & 63;
    int m = lane & 15, q = lane >> 4;
    const char* tb0 = (const char*)tblH + q*16;
    const char* tb1 = tb0 + 2080;
    const char* tb2 = tb1 + 2080;

    float accp[32];              // pooled partials, k = ki*32+q*8+t
    #pragma unroll
    for (int j = 0; j < 32; j++) accp[j] = 0.f;
    float Mw = -3e38f, Sw = 0.f;

    #pragma unroll
    for (int it = 0; it < 2; it++){
        int base = w*32 + it*16 + m;
        uint4 vfr[4];            // B-frags: lane's own position, 4 K-tiles
        {
            unsigned V[4][4];    // V[s][ki] = f16x2(chA,chB); cp=ki*4+q
            #pragma unroll
            for (int s = 0; s < 4; s++){
                unsigned oa = seqw16[s][base];
                unsigned ob = seqw16[s][base+1];
                unsigned oc = seqw16[s][base+2];
                uint4 t0 = *(const uint4*)(tb0 + oa);
                uint4 t1 = *(const uint4*)(tb1 + ob);
                uint4 t2 = *(const uint4*)(tb2 + oc);
                V[s][0] = h3relu(t0.x, t1.x, t2.x);
                V[s][1] = h3relu(t0.y, t1.y, t2.y);
                V[s][2] = h3relu(t0.z, t1.z, t2.z);
                V[s][3] = h3relu(t0.w, t1.w, t2.w);
            }
            #pragma unroll
            for (int ki = 0; ki < 4; ki++){
                uint4 o;
                o.x = __builtin_amdgcn_perm(V[1][ki], V[0][ki], 0x05040100u);  // A_s0,A_s1
                o.y = __builtin_amdgcn_perm(V[3][ki], V[2][ki], 0x05040100u);  // A_s2,A_s3
                o.z = __builtin_amdgcn_perm(V[1][ki], V[0][ki], 0x07060302u);  // B_s0,B_s1
                o.w = __builtin_amdgcn_perm(V[3][ki], V[2][ki], 0x07060302u);  // B_s2,B_s3
                vfr[ki] = o;
            }
        }

        // d_out in two halves of 4 dt-tiles: per ki, 4 batched A-reads then
        // 4 MFMAs into distinct accs (dep dist 4); acc dies into tanh/ep
        // before the next half. ep order: dt ascending, elem ascending.
        float ep = 0.f;
        #pragma unroll
        for (int h = 0; h < 2; h++){
            f32x4 acc[4];
            #pragma unroll
            for (int dd = 0; dd < 4; dd++) acc[dd] = (f32x4){0.f, 0.f, 0.f, 0.f};
            #pragma unroll
            for (int ki = 0; ki < 4; ki++){
                uint4 af[4];
                #pragma unroll
                for (int dd = 0; dd < 4; dd++){
                    int dt = h*4 + dd;
                    unsigned abyte = (unsigned)((dt*16 + m)*256 + ki*64 + q*16)
                                   ^ (((unsigned)(m & 7)) << 4);
                    af[dd] = *(const uint4*)((const char*)wahL + abyte);
                }
                union { uint4 u; f16x8 f; } bf; bf.u = vfr[ki];
                #pragma unroll
                for (int dd = 0; dd < 4; dd++){
                    union { uint4 u; f16x8 f; } a; a.u = af[dd];
                    acc[dd] = __builtin_amdgcn_mfma_f32_16x16x32_f16(a.f, bf.f, acc[dd], 0, 0, 0);
                }
            }
            #pragma unroll
            for (int dd = 0; dd < 4; dd++){
                int dt = h*4 + dd;
                const f32x4 vg = *(const f32x4*)&vaL[dt*16 + q*4];
                ep += vg[0] * tanh_fast(acc[dd][0]);
                ep += vg[1] * tanh_fast(acc[dd][1]);
                ep += vg[2] * tanh_fast(acc[dd][2]);
                ep += vg[3] * tanh_fast(acc[dd][3]);
            }
        }
        ep += __shfl_xor(ep, 16);
        ep += __shfl_xor(ep, 32);        // e[col m], replicated across q

        // online softmax over this 16-position tile (16-lane butterfly)
        float msub = ep;
        #pragma unroll
        for (int off = 8; off >= 1; off >>= 1)
            msub = fmaxf(msub, __shfl_xor(msub, off));
        float Mnew = fmaxf(Mw, msub);
        float alpha = __expf(Mw - Mnew);
        float wrl = __expf(ep - Mnew);   // weight of THIS lane's own position
        float ssub = wrl;
        #pragma unroll
        for (int off = 8; off >= 1; off >>= 1) ssub += __shfl_xor(ssub, off);
        Sw = alpha * Sw + ssub;
        Mw = Mnew;

        // pool from the lane's OWN V registers (no LDS, no shfl)
        #pragma unroll
        for (int ki = 0; ki < 4; ki++){
            union { uint4 u; f16x2 h[4]; } vv; vv.u = vfr[ki];
            accp[ki*8 + 0] = alpha * accp[ki*8 + 0] + wrl * (float)vv.h[0][0];
            accp[ki*8 + 1] = alpha * accp[ki*8 + 1] + wrl * (float)vv.h[0][1];
            accp[ki*8 + 2] = alpha * accp[ki*8 + 2] + wrl * (float)vv.h[1][0];
            accp[ki*8 + 3] = alpha * accp[ki*8 + 3] + wrl * (float)vv.h[1][1];
            accp[ki*8 + 4] = alpha * accp[ki*8 + 4] + wrl * (float)vv.h[2][0];
            accp[ki*8 + 5] = alpha * accp[ki*8 + 5] + wrl * (float)vv.h[2][1];
            accp[ki*8 + 6] = alpha * accp[ki*8 + 6] + wrl * (float)vv.h[3][0];
            accp[ki*8 + 7] = alpha * accp[ki*8 + 7] + wrl * (float)vv.h[3][1];
        }
    }

    // reduce accp over the 16 position-lanes (m); k-slice differs only by q
    #pragma unroll
    for (int j = 0; j < 32; j++){
        accp[j] += __shfl_xor(accp[j], 1);
        accp[j] += __shfl_xor(accp[j], 2);
        accp[j] += __shfl_xor(accp[j], 4);
        accp[j] += __shfl_xor(accp[j], 8);
    }
    size_t chunk = ((size_t)b*16 + x)*4 + w;      // 64 chunks per b, c = pos/32
    if (m == 0){
        float* pd = part + chunk*128;
        #pragma unroll
        for (int ki = 0; ki < 4; ki++){
            float4 lo = { accp[ki*8+0], accp[ki*8+1], accp[ki*8+2], accp[ki*8+3] };
            float4 hi = { accp[ki*8+4], accp[ki*8+5], accp[ki*8+6], accp[ki*8+7] };
            *(float4*)(pd + ki*32 + q*8)     = lo;   // 16B-aligned (elem%4==0)
            *(float4*)(pd + ki*32 + q*8 + 4) = hi;
        }
    }
    if (lane == 0){
        stats[chunk*2    ] = Mw;
        stats[chunk*2 + 1] = Sw;
    }
}

// KB2: combine 64 chunk partials per b with softmax rescale.
// out[b][d] = sum_c part[b][c][d]*exp(m_c-M) / sum_c s_c*exp(m_c-M)
__global__ __launch_bounds__(128) void kb2_finish(const float* __restrict__ part,
        const float* __restrict__ stats, float* __restrict__ out)
{
    int b = blockIdx.x, d = threadIdx.x;
    const float* st = stats + (size_t)b*128;
    float M = -3e38f;
    #pragma unroll 8
    for (int c = 0; c < 64; c++) M = fmaxf(M, st[c*2]);
    const float* p = part + (size_t)b*64*128 + d;
    float S = 0.f, s = 0.f;
    #pragma unroll 4
    for (int c = 0; c < 64; c++){
        float f = __expf(st[c*2] - M);
        S += st[c*2+1] * f;
        s += p[c*128] * f;
    }
    float inv = 1.0f / S;
    out[b*128 + d] = s * inv;
}

extern "C" void kernel_launch(void* const* d_in, const int* in_sizes, int n_in,
                              void* d_out, int out_size, void* d_ws, size_t ws_size,
                              hipStream_t stream)
{
    const int*   seq = (const int*)d_in[0];
    const float* emb = (const float*)d_in[1];
    const float* cw  = (const float*)d_in[2];
    const float* cb  = (const float*)d_in[3];
    const float* Wa  = (const float*)d_in[4];
    const float* va  = (const float*)d_in[5];
    float* out = (float*)d_out;

    char* wsb = (char*)d_ws;
    float*    part  = (float*)wsb;                       // 4 MiB (128*64*128 f32)
    float*    stats = (float*)(wsb + (8<<20));           // 64 KiB (128*64*2 f32)
    unsigned* tblG  = (unsigned*)(wsb + (12<<20));       // 6240 B
    unsigned* wahG  = (unsigned*)(wsb + (12<<20) + 32768); // 32 KiB (swizzled image)

    k_setup   <<<5,            256, 0, stream>>>(emb, cw, cb, Wa, tblG, wahG);
    k_fused   <<<dim3(16,128), 256, 0, stream>>>(seq, tblG, wahG, va, part, stats);
    kb2_finish<<<128,          128, 0, stream>>>(part, stats, out);
}